// Round 4
// baseline (445.277 us; speedup 1.0000x reference)
//
#include <hip/hip_runtime.h>

// Problem constants (match reference setup_inputs)
#define Bz 2
#define Dz 160
#define Hz 192
#define Wz 160
#define HWl (Hz*Wz)           // 30720
#define DHWl (Dz*Hz*Wz)       // 4915200

// LNCC tiling: 256-thread blocks, 16x16 in-plane tile, 20-slice D walk.
// Round-3 post-mortem: 512thr/16x32/DT32 gave 600 blocks = 2.3/CU, 29%
// occupancy, latency-bound at barriers (VALUBusy 36%, HBM 13%, conflicts 0).
// This tiling gives 1920 blocks (7.5/CU), 4-wave barrier groups, 12.3KB LDS.
#define TH 16
#define TW 16
#define DT 20
#define RAWH (TH+8)           // 24
#define RAWW (TW+8)           // 24
#define NB_H (Hz/TH)          // 12
#define NB_W (Wz/TW)          // 10
#define NB_D (Dz/DT)          // 8
#define LNCC_BLOCKS (Bz*NB_H*NB_W*NB_D)  // 1920
#define LNCC_THREADS 256
#define NSLICE (DT+8)         // 28

// Flow gradient
#define FLOW_BLOCKS 2048
#define FLOW_THREADS 256
#define FLOW_N4 ((Bz*3*DHWl)/4)          // 7372800 float4s

// ws layout: nbuck buckets x 4 doubles {cc, d, h, w}. nbuck<=64, computed
// from ws_size so this works for ANY ws_size >= 32B (round-3 evidence says
// ws_size < 54KB, which silently forced the contended-atomic fallback:
// flow ~180us for a <=60us stream = 2048 same-address f64 atomics).
#define MAXBUCK 64

__global__ __launch_bounds__(LNCC_THREADS, 6)
void lncc_kernel(const float* __restrict__ F, const float* __restrict__ M,
                 double* __restrict__ ws, int nbuck) {
    __shared__ float2 raw[RAWH][RAWW];     // (f, m) raw slice tile, zero-padded halo
    __shared__ float4 wbv[RAWH][TW];       // W-boxed: (Sf, Sm, Sff, Smm)
    __shared__ float  wbs[RAWH][TW];       // W-boxed: Sfm
    __shared__ double wred[LNCC_THREADS/64];

    const int bid = blockIdx.x;
    const int dc = bid % NB_D;
    const int wc = (bid / NB_D) % NB_W;
    const int hc = (bid / (NB_D * NB_W)) % NB_H;
    const int b  = bid / (NB_D * NB_W * NB_H);

    const int tid = threadIdx.x;
    const int th = tid >> 4;       // 0..15
    const int tw = tid & 15;       // 0..15

    const int h0 = hc * TH;
    const int w0 = wc * TW;
    const int d0 = dc * DT;
    const size_t bbase = (size_t)b * DHWl;

    // 9-slice rolling window of H-boxed values; all indices compile-time
    // (q from the unrolled loop) so SROA keeps it in VGPRs (round-1 lesson:
    // runtime slot -> 490MB scratch traffic).
    float circ[9][5];
#pragma unroll
    for (int i = 0; i < 9; ++i)
#pragma unroll
        for (int j = 0; j < 5; ++j) circ[i][j] = 0.f;
    float rs0 = 0.f, rs1 = 0.f, rs2 = 0.f, rs3 = 0.f, rs4 = 0.f;
    float cc_acc = 0.f;

    for (int i0 = 0; i0 < NSLICE; i0 += 9) {
#pragma unroll
        for (int q = 0; q < 9; ++q) {
            const int i = i0 + q;              // slice index within walk
            if (i < NSLICE) {                  // uniform guard
                const int s = d0 - 4 + i;      // global D slice
                float nv0 = 0.f, nv1 = 0.f, nv2 = 0.f, nv3 = 0.f, nv4 = 0.f;
                if (s >= 0 && s < Dz) {        // block-uniform branch
                    __syncthreads();           // protect previous slice's LDS reads
                    // ---- stage raw slice (zero outside volume) ----
                    const size_t sbase = bbase + (size_t)s * HWl;
                    for (int k = tid; k < RAWH * RAWW; k += LNCC_THREADS) {
                        const int r = k / RAWW;
                        const int c = k - r * RAWW;
                        const int gh = h0 - 4 + r;
                        const int gw = w0 - 4 + c;
                        float fv = 0.f, mv = 0.f;
                        if (gh >= 0 && gh < Hz && gw >= 0 && gw < Wz) {
                            const size_t gi = sbase + (size_t)gh * Wz + gw;
                            fv = F[gi];
                            mv = M[gi];
                        }
                        raw[r][c] = make_float2(fv, mv);
                    }
                    __syncthreads();
                    // ---- W-box: 9-tap sums of the 5 products ----
                    for (int k = tid; k < RAWH * TW; k += LNCC_THREADS) {
                        const int r = k >> 4;
                        const int j = k & 15;
                        float sf = 0.f, sm = 0.f, sff = 0.f, smm = 0.f, sfm = 0.f;
#pragma unroll
                        for (int t = 0; t < 9; ++t) {
                            const float2 fm = raw[r][j + t];
                            sf  += fm.x;
                            sm  += fm.y;
                            sff += fm.x * fm.x;
                            smm += fm.y * fm.y;
                            sfm += fm.x * fm.y;
                        }
                        wbv[r][j] = make_float4(sf, sm, sff, smm);
                        wbs[r][j] = sfm;
                    }
                    __syncthreads();
                    // ---- H-box: 9 taps over W-boxed rows ----
#pragma unroll
                    for (int t = 0; t < 9; ++t) {
                        const float4 v = wbv[th + t][tw];
                        nv0 += v.x; nv1 += v.y; nv2 += v.z; nv3 += v.w;
                        nv4 += wbs[th + t][tw];
                    }
                }
                // ---- rolling D update: compile-time slot q ----
                rs0 += nv0 - circ[q][0]; circ[q][0] = nv0;
                rs1 += nv1 - circ[q][1]; circ[q][1] = nv1;
                rs2 += nv2 - circ[q][2]; circ[q][2] = nv2;
                rs3 += nv3 - circ[q][3]; circ[q][3] = nv3;
                rs4 += nv4 - circ[q][4]; circ[q][4] = nv4;
                if (i >= 8) {                  // out_d = d0 + (i-8)
                    const float inv_n = 1.0f / 729.0f;
                    const float mf   = rs0 * inv_n;
                    const float mm   = rs1 * inv_n;
                    const float varf = rs2 - mf * mf;
                    const float varm = rs3 - mm * mm;
                    const float cov  = rs4 - mf * mm;
                    const float cc = cov * cov / (varf * varm + 1e-8f);
                    cc_acc += cc;
                }
            }
        }
    }

    // ---- reduce cc_acc over block, one bucketed atomic ----
    double v = (double)cc_acc;
#pragma unroll
    for (int off = 32; off > 0; off >>= 1) v += __shfl_down(v, off);
    const int wave = tid >> 6, lane = tid & 63;
    if (lane == 0) wred[wave] = v;
    __syncthreads();
    if (tid == 0) {
        double t = 0.0;
        for (int k = 0; k < LNCC_THREADS / 64; ++k) t += wred[k];
        const int bucket = bid % nbuck;
        atomicAdd(&ws[bucket * 4 + 0], t);
    }
}

// Flow gradient: backward diffs along D, H, W. Bucketed f64 atomics.
__global__ __launch_bounds__(FLOW_THREADS)
void flow_grad_kernel(const float* __restrict__ X, double* __restrict__ ws, int nbuck) {
    __shared__ double wr0[4], wr1[4], wr2[4];
    float sd = 0.f, sh = 0.f, sw = 0.f;
    const int stride = gridDim.x * blockDim.x;
    for (int i4 = blockIdx.x * blockDim.x + threadIdx.x; i4 < FLOW_N4; i4 += stride) {
        const int base = i4 * 4;                     // < 2^31, safe
        const float4 v = *(const float4*)(X + base);
        const int pos  = base % DHWl;                // position within (b,c) volume
        const int w    = pos % Wz;
        const int rest = pos / Wz;
        const int h    = rest % Hz;
        const int d    = rest / Hz;
        // W diffs (within-row; W divisible by 4 so float4 never crosses a row)
        float s = fabsf(v.y - v.x) + fabsf(v.z - v.y) + fabsf(v.w - v.z);
        if (w > 0) s += fabsf(v.x - X[base - 1]);
        sw += s;
        if (h > 0) {
            const float4 u = *(const float4*)(X + base - Wz);
            sh += fabsf(v.x - u.x) + fabsf(v.y - u.y) + fabsf(v.z - u.z) + fabsf(v.w - u.w);
        }
        if (d > 0) {
            const float4 u = *(const float4*)(X + base - HWl);
            sd += fabsf(v.x - u.x) + fabsf(v.y - u.y) + fabsf(v.z - u.z) + fabsf(v.w - u.w);
        }
    }
    double a = (double)sd, b = (double)sh, c = (double)sw;
#pragma unroll
    for (int off = 32; off > 0; off >>= 1) {
        a += __shfl_down(a, off);
        b += __shfl_down(b, off);
        c += __shfl_down(c, off);
    }
    const int wave = threadIdx.x >> 6, lane = threadIdx.x & 63;
    if (lane == 0) { wr0[wave] = a; wr1[wave] = b; wr2[wave] = c; }
    __syncthreads();
    if (threadIdx.x == 0) {
        double ta = 0.0, tb = 0.0, tc = 0.0;
        for (int k = 0; k < 4; ++k) { ta += wr0[k]; tb += wr1[k]; tc += wr2[k]; }
        const int bucket = (int)(blockIdx.x % (unsigned)nbuck);
        double* p = ws + bucket * 4;
        atomicAdd(&p[1], ta);   // D diffs (reference "dy")
        atomicAdd(&p[2], tb);   // H diffs (reference "dx")
        atomicAdd(&p[3], tc);   // W diffs (reference "dz")
    }
}

__global__ __launch_bounds__(64)
void finalize_kernel(const double* __restrict__ ws, float* __restrict__ out, int nbuck) {
    const int tid = threadIdx.x;
    double cc = 0.0, sd = 0.0, sh = 0.0, sw = 0.0;
    if (tid < nbuck) {
        const double* p = ws + tid * 4;
        cc = p[0]; sd = p[1]; sh = p[2]; sw = p[3];
    }
#pragma unroll
    for (int off = 32; off > 0; off >>= 1) {
        cc += __shfl_down(cc, off);
        sd += __shfl_down(sd, off);
        sh += __shfl_down(sh, off);
        sw += __shfl_down(sw, off);
    }
    if (tid == 0) {
        const double n_cc = 9830400.0;           // 2*1*160*192*160
        const double n_dx = 29337600.0;          // H diffs: 2*3*160*191*160
        const double n_dy = 29306880.0;          // D diffs: 2*3*159*192*160
        const double n_dz = 29306880.0;          // W diffs: 2*3*160*192*159
        const double L_sim = -cc / n_cc;
        const double L_reg = sh / n_dx + sd / n_dy + sw / n_dz;
        out[0] = (float)(L_sim + L_reg);
        out[1] = (float)L_sim;
        out[2] = (float)L_reg;
    }
}

extern "C" void kernel_launch(void* const* d_in, const int* in_sizes, int n_in,
                              void* d_out, int out_size, void* d_ws, size_t ws_size,
                              hipStream_t stream) {
    (void)in_sizes; (void)n_in; (void)out_size;
    const float* F = (const float*)d_in[0];   // I_fixed
    const float* M = (const float*)d_in[1];   // I_moved
    const float* X = (const float*)d_in[2];   // flow
    double* ws = (double*)d_ws;
    float* out = (float*)d_out;

    int nbuck = (int)(ws_size / (4 * sizeof(double)));
    if (nbuck > MAXBUCK) nbuck = MAXBUCK;
    if (nbuck < 1) nbuck = 1;

    hipMemsetAsync(d_ws, 0, (size_t)nbuck * 4 * sizeof(double), stream);
    lncc_kernel<<<LNCC_BLOCKS, LNCC_THREADS, 0, stream>>>(F, M, ws, nbuck);
    flow_grad_kernel<<<FLOW_BLOCKS, FLOW_THREADS, 0, stream>>>(X, ws, nbuck);
    finalize_kernel<<<1, 64, 0, stream>>>(ws, out, nbuck);
}

// Round 8
// 374.916 us; speedup vs baseline: 1.1877x; 1.1877x over previous
//
#include <hip/hip_runtime.h>

// Problem constants (match reference setup_inputs)
#define Bz 2
#define Dz 160
#define Hz 192
#define Wz 160
#define HWl (Hz*Wz)           // 30720
#define DHWl (Dz*Hz*Wz)       // 4915200

// LNCC tiling: 256-thread blocks, 16x16 in-plane tile, 20-slice D walk.
// R4 post-mortem: __launch_bounds__(256,6) forced VGPR=40 < the ~56 the
// rolling circ[9][5] needs -> re-spill (WRITE_SIZE 290MB). Use (256,2):
// R3 showed the same code fits in 56 VGPR with no spill at that bound.
#define TH 16
#define TW 16
#define DT 20
#define RAWH (TH+8)           // 24
#define RAWW (TW+8)           // 24
#define NB_H (Hz/TH)          // 12
#define NB_W (Wz/TW)          // 10
#define NB_D (Dz/DT)          // 8
#define LNCC_BLOCKS (Bz*NB_H*NB_W*NB_D)  // 1920
#define LNCC_THREADS 256
#define NSLICE (DT+8)         // 28

// Flow: one block per (b,c,d) slice
#define FLOW_BLOCKS (Bz*3*Dz)            // 960
#define FLOW_THREADS 256
#define W4 (Wz/4)                        // 40
#define SLICE_N4 (Hz*W4)                 // 7680 float4s per slice

// ws layouts.
// mode1 (ws_size >= 40KB): zero-atomic two-phase.
//   ws[0..1919]              lncc per-block partials
//   ws[FPO + 3*fb + {0,1,2}] flow per-block partials (d,h,w)
// mode0: nbuck buckets x 4 doubles {cc,d,h,w}, bucketed atomics.
#define FPO LNCC_BLOCKS                       // 1920
#define WS_MODE1_DBL (FPO + 3*FLOW_BLOCKS)    // 4800 doubles = 38.4KB
#define MAXBUCK 64

__global__ __launch_bounds__(LNCC_THREADS, 2)
void lncc_kernel(const float* __restrict__ F, const float* __restrict__ M,
                 double* __restrict__ ws, int nbuck, int mode) {
    __shared__ float2 raw[RAWH][RAWW];     // raw slice tile (f,m), zero-padded halo
    __shared__ float4 wbv[RAWH][TW + 1];   // W-boxed (Sf,Sm,Sff,Smm); +1 pad breaks
    __shared__ float  wbs[RAWH][TW + 1];   //   256B row alignment (R4: 622K conflicts)
    __shared__ double wred[LNCC_THREADS/64];

    const int bid = blockIdx.x;
    const int dc = bid % NB_D;
    const int wc = (bid / NB_D) % NB_W;
    const int hc = (bid / (NB_D * NB_W)) % NB_H;
    const int b  = bid / (NB_D * NB_W * NB_H);

    const int tid = threadIdx.x;
    const int th = tid >> 4;       // 0..15
    const int tw = tid & 15;       // 0..15

    const int h0 = hc * TH;
    const int w0 = wc * TW;
    const int d0 = dc * DT;
    const size_t bbase = (size_t)b * DHWl;

    // 9-slice rolling window; all indices compile-time (q from unrolled loop)
    // so SROA keeps it in VGPRs (R1 lesson: runtime slot -> 490MB scratch).
    float circ[9][5];
#pragma unroll
    for (int i = 0; i < 9; ++i)
#pragma unroll
        for (int j = 0; j < 5; ++j) circ[i][j] = 0.f;
    float rs0 = 0.f, rs1 = 0.f, rs2 = 0.f, rs3 = 0.f, rs4 = 0.f;
    float cc_acc = 0.f;

    for (int i0 = 0; i0 < NSLICE; i0 += 9) {
#pragma unroll
        for (int q = 0; q < 9; ++q) {
            const int i = i0 + q;              // slice index within walk
            if (i < NSLICE) {                  // uniform guard
                const int s = d0 - 4 + i;      // global D slice
                float nv0 = 0.f, nv1 = 0.f, nv2 = 0.f, nv3 = 0.f, nv4 = 0.f;
                if (s >= 0 && s < Dz) {        // block-uniform branch
                    __syncthreads();           // protect previous slice's LDS reads
                    // ---- stage raw slice (zero outside volume) ----
                    const size_t sbase = bbase + (size_t)s * HWl;
                    for (int k = tid; k < RAWH * RAWW; k += LNCC_THREADS) {
                        const int r = k / RAWW;
                        const int c = k - r * RAWW;
                        const int gh = h0 - 4 + r;
                        const int gw = w0 - 4 + c;
                        float fv = 0.f, mv = 0.f;
                        if (gh >= 0 && gh < Hz && gw >= 0 && gw < Wz) {
                            const size_t gi = sbase + (size_t)gh * Wz + gw;
                            fv = F[gi];
                            mv = M[gi];
                        }
                        raw[r][c] = make_float2(fv, mv);
                    }
                    __syncthreads();
                    // ---- W-box: 9-tap sums of the 5 products ----
                    for (int k = tid; k < RAWH * TW; k += LNCC_THREADS) {
                        const int r = k >> 4;
                        const int j = k & 15;
                        float sf = 0.f, sm = 0.f, sff = 0.f, smm = 0.f, sfm = 0.f;
#pragma unroll
                        for (int t = 0; t < 9; ++t) {
                            const float2 fm = raw[r][j + t];
                            sf  += fm.x;
                            sm  += fm.y;
                            sff += fm.x * fm.x;
                            smm += fm.y * fm.y;
                            sfm += fm.x * fm.y;
                        }
                        wbv[r][j] = make_float4(sf, sm, sff, smm);
                        wbs[r][j] = sfm;
                    }
                    __syncthreads();
                    // ---- H-box: 9 taps over W-boxed rows ----
#pragma unroll
                    for (int t = 0; t < 9; ++t) {
                        const float4 v = wbv[th + t][tw];
                        nv0 += v.x; nv1 += v.y; nv2 += v.z; nv3 += v.w;
                        nv4 += wbs[th + t][tw];
                    }
                }
                // ---- rolling D update: compile-time slot q ----
                rs0 += nv0 - circ[q][0]; circ[q][0] = nv0;
                rs1 += nv1 - circ[q][1]; circ[q][1] = nv1;
                rs2 += nv2 - circ[q][2]; circ[q][2] = nv2;
                rs3 += nv3 - circ[q][3]; circ[q][3] = nv3;
                rs4 += nv4 - circ[q][4]; circ[q][4] = nv4;
                if (i >= 8) {                  // out_d = d0 + (i-8)
                    const float inv_n = 1.0f / 729.0f;
                    const float mf   = rs0 * inv_n;
                    const float mm   = rs1 * inv_n;
                    const float varf = rs2 - mf * mf;
                    const float varm = rs3 - mm * mm;
                    const float cov  = rs4 - mf * mm;
                    const float cc = cov * cov / (varf * varm + 1e-8f);
                    cc_acc += cc;
                }
            }
        }
    }

    // ---- block reduction ----
    double v = (double)cc_acc;
#pragma unroll
    for (int off = 32; off > 0; off >>= 1) v += __shfl_down(v, off);
    const int wave = tid >> 6, lane = tid & 63;
    if (lane == 0) wred[wave] = v;
    __syncthreads();
    if (tid == 0) {
        double t = 0.0;
        for (int k = 0; k < LNCC_THREADS / 64; ++k) t += wred[k];
        if (mode) ws[bid] = t;                       // private slot, no atomic
        else      atomicAdd(&ws[(bid % nbuck) * 4 + 0], t);
    }
}

// Flow gradient: one block per (b,c,d) slice. No big-constant div/mod in the
// inner loop; W-neighbor via __shfl_up (lane 0 falls back to a cached scalar).
__global__ __launch_bounds__(FLOW_THREADS)
void flow_grad_kernel(const float* __restrict__ X, double* __restrict__ ws,
                      int nbuck, int mode) {
    __shared__ double wr0[4], wr1[4], wr2[4];
    const int fb = blockIdx.x;
    const int d  = fb % Dz;
    const int bc = fb / Dz;
    const float* S = X + (size_t)bc * DHWl + (size_t)d * HWl;
    const int lane = threadIdx.x & 63;

    float sd = 0.f, sh = 0.f, sw = 0.f;
    for (int k4 = threadIdx.x; k4 < SLICE_N4; k4 += FLOW_THREADS) {
        const int h  = k4 / W4;              // div by 40 (compile-time magic)
        const int w4 = k4 - h * W4;
        const int base = h * Wz + w4 * 4;
        const float4 v = *(const float4*)(S + base);
        float left = __shfl_up(v.w, 1);      // lane l-1 holds k4-1 = base-4..base-1
        float s = fabsf(v.y - v.x) + fabsf(v.z - v.y) + fabsf(v.w - v.z);
        if (w4 > 0) {
            if (lane == 0) left = S[base - 1];
            s += fabsf(v.x - left);
        }
        sw += s;
        if (h > 0) {
            const float4 u = *(const float4*)(S + base - Wz);
            sh += fabsf(v.x - u.x) + fabsf(v.y - u.y) + fabsf(v.z - u.z) + fabsf(v.w - u.w);
        }
        if (d > 0) {                         // block-uniform
            const float4 u = *(const float4*)(S + base - HWl);
            sd += fabsf(v.x - u.x) + fabsf(v.y - u.y) + fabsf(v.z - u.z) + fabsf(v.w - u.w);
        }
    }
    double a = (double)sd, b = (double)sh, c = (double)sw;
#pragma unroll
    for (int off = 32; off > 0; off >>= 1) {
        a += __shfl_down(a, off);
        b += __shfl_down(b, off);
        c += __shfl_down(c, off);
    }
    const int wave = threadIdx.x >> 6;
    if (lane == 0) { wr0[wave] = a; wr1[wave] = b; wr2[wave] = c; }
    __syncthreads();
    if (threadIdx.x == 0) {
        double ta = 0.0, tb = 0.0, tc = 0.0;
        for (int k = 0; k < 4; ++k) { ta += wr0[k]; tb += wr1[k]; tc += wr2[k]; }
        if (mode) {
            double* p = ws + FPO + 3 * (size_t)fb;
            p[0] = ta; p[1] = tb; p[2] = tc;        // private slots, no atomics
        } else {
            double* p = ws + (fb % nbuck) * 4;
            atomicAdd(&p[1], ta);
            atomicAdd(&p[2], tb);
            atomicAdd(&p[3], tc);
        }
    }
}

__global__ __launch_bounds__(512)
void finalize_kernel(const double* __restrict__ ws, float* __restrict__ out,
                     int nbuck, int mode) {
    __shared__ double red[4][8];
    const int tid = threadIdx.x;
    double cc = 0.0, sd = 0.0, sh = 0.0, sw = 0.0;
    if (mode) {
        for (int i = tid; i < LNCC_BLOCKS; i += 512) cc += ws[i];
        for (int i = tid; i < FLOW_BLOCKS; i += 512) {
            const double* p = ws + FPO + 3 * (size_t)i;
            sd += p[0]; sh += p[1]; sw += p[2];
        }
    } else if (tid < nbuck) {
        const double* p = ws + tid * 4;
        cc = p[0]; sd = p[1]; sh = p[2]; sw = p[3];
    }
#pragma unroll
    for (int off = 32; off > 0; off >>= 1) {
        cc += __shfl_down(cc, off);
        sd += __shfl_down(sd, off);
        sh += __shfl_down(sh, off);
        sw += __shfl_down(sw, off);
    }
    const int wave = tid >> 6, lane = tid & 63;
    if (lane == 0) { red[0][wave] = cc; red[1][wave] = sd; red[2][wave] = sh; red[3][wave] = sw; }
    __syncthreads();
    if (tid == 0) {
        double tcc = 0.0, tsd = 0.0, tsh = 0.0, tsw = 0.0;
        for (int k = 0; k < 8; ++k) {
            tcc += red[0][k]; tsd += red[1][k]; tsh += red[2][k]; tsw += red[3][k];
        }
        const double n_cc = 9830400.0;           // 2*1*160*192*160
        const double n_dx = 29337600.0;          // H diffs: 2*3*160*191*160
        const double n_dy = 29306880.0;          // D diffs: 2*3*159*192*160
        const double n_dz = 29306880.0;          // W diffs: 2*3*160*192*159
        const double L_sim = -tcc / n_cc;
        const double L_reg = tsh / n_dx + tsd / n_dy + tsw / n_dz;
        out[0] = (float)(L_sim + L_reg);
        out[1] = (float)L_sim;
        out[2] = (float)L_reg;
    }
}

extern "C" void kernel_launch(void* const* d_in, const int* in_sizes, int n_in,
                              void* d_out, int out_size, void* d_ws, size_t ws_size,
                              hipStream_t stream) {
    (void)in_sizes; (void)n_in; (void)out_size;
    const float* F = (const float*)d_in[0];   // I_fixed
    const float* M = (const float*)d_in[1];   // I_moved
    const float* X = (const float*)d_in[2];   // flow
    double* ws = (double*)d_ws;
    float* out = (float*)d_out;

    const int mode = (ws_size >= WS_MODE1_DBL * sizeof(double)) ? 1 : 0;
    int nbuck = 1;
    if (!mode) {
        nbuck = (int)(ws_size / (4 * sizeof(double)));
        if (nbuck > MAXBUCK) nbuck = MAXBUCK;
        if (nbuck < 1) nbuck = 1;
        hipMemsetAsync(d_ws, 0, (size_t)nbuck * 4 * sizeof(double), stream);
    }

    lncc_kernel<<<LNCC_BLOCKS, LNCC_THREADS, 0, stream>>>(F, M, ws, nbuck, mode);
    flow_grad_kernel<<<FLOW_BLOCKS, FLOW_THREADS, 0, stream>>>(X, ws, nbuck, mode);
    finalize_kernel<<<1, 512, 0, stream>>>(ws, out, nbuck, mode);
}

// Round 9
// 368.468 us; speedup vs baseline: 1.2085x; 1.0175x over previous
//
#include <hip/hip_runtime.h>

// Problem constants (match reference setup_inputs)
#define Bz 2
#define Dz 160
#define Hz 192
#define Wz 160
#define HWl (Hz*Wz)           // 30720
#define DHWl (Dz*Hz*Wz)       // 4915200

// LNCC tiling: 256-thread blocks, 16x16 tile, 20-slice D walk (1920 blocks).
#define TH 16
#define TW 16
#define DT 20
#define RAWH (TH+8)           // 24
#define RAWW (TW+8)           // 24
#define NB_H (Hz/TH)          // 12
#define NB_W (Wz/TW)          // 10
#define NB_D (Dz/DT)          // 8
#define NBLOCKS (Bz*NB_H*NB_W*NB_D)  // 1920
#define NTHREADS 256
#define NSLICE (DT+8)         // 28

// Flow fused as a grid-stride tail over float4s of the flow field.
#define FLOW_N4 ((Bz*3*DHWl)/4)      // 7372800
#define FSTRIDE (NBLOCKS*NTHREADS)   // 491520 -> exactly 15 iters/thread

// ws: nbuck buckets x 4 doubles {cc, d, h, w}; bucketed f64 atomics
// (1920 blocks / <=64 buckets = <=30 collisions per address, negligible).
#define MAXBUCK 64

__global__ __launch_bounds__(NTHREADS, 2)
void fused_kernel(const float* __restrict__ F, const float* __restrict__ M,
                  const float* __restrict__ X, double* __restrict__ ws, int nbuck) {
    __shared__ float2 raw[RAWH][RAWW];     // raw slice tile (f,m), zero-padded halo
    __shared__ float4 wbv[RAWH][TW + 1];   // W-boxed (Sf,Sm,Sff,Smm), stride 17 f4
    __shared__ float  wbs[RAWH][TW + 1];   // W-boxed Sfm
    __shared__ double wred[4][NTHREADS/64];

    const int bid = blockIdx.x;
    const int dc = bid % NB_D;
    const int wc = (bid / NB_D) % NB_W;
    const int hc = (bid / (NB_D * NB_W)) % NB_H;
    const int b  = bid / (NB_D * NB_W * NB_H);

    const int tid = threadIdx.x;
    // R8 post-mortem: th=tid>>4 made the H-box b128 read an 8-distinct-address
    // per-bank-group pattern (12.4M conflict cycles). Swapped mapping: 16
    // consecutive lanes read rows 0..15 at stride 17 f4 (== 1 mod 8) -> one
    // lane per bank-group per 128B phase, the clean minimum for ds_read_b128.
    const int th = tid & 15;       // output row within tile
    const int tw = tid >> 4;       // output col within tile

    const int h0 = hc * TH;
    const int w0 = wc * TW;
    const int d0 = dc * DT;
    const size_t bbase = (size_t)b * DHWl;

    // 9-slice rolling window; all indices compile-time (q from unrolled loop)
    // so SROA keeps it in VGPRs (R1 lesson: runtime slot -> 490MB scratch).
    float circ[9][5];
#pragma unroll
    for (int i = 0; i < 9; ++i)
#pragma unroll
        for (int j = 0; j < 5; ++j) circ[i][j] = 0.f;
    float rs0 = 0.f, rs1 = 0.f, rs2 = 0.f, rs3 = 0.f, rs4 = 0.f;
    float cc_acc = 0.f;

    for (int i0 = 0; i0 < NSLICE; i0 += 9) {
#pragma unroll
        for (int q = 0; q < 9; ++q) {
            const int i = i0 + q;              // slice index within walk
            if (i < NSLICE) {                  // uniform guard
                const int s = d0 - 4 + i;      // global D slice
                float nv0 = 0.f, nv1 = 0.f, nv2 = 0.f, nv3 = 0.f, nv4 = 0.f;
                if (s >= 0 && s < Dz) {        // block-uniform branch
                    __syncthreads();           // protect previous slice's LDS reads
                    // ---- stage raw slice (zero outside volume) ----
                    const size_t sbase = bbase + (size_t)s * HWl;
                    for (int k = tid; k < RAWH * RAWW; k += NTHREADS) {
                        const int r = k / RAWW;
                        const int c = k - r * RAWW;
                        const int gh = h0 - 4 + r;
                        const int gw = w0 - 4 + c;
                        float fv = 0.f, mv = 0.f;
                        if (gh >= 0 && gh < Hz && gw >= 0 && gw < Wz) {
                            const size_t gi = sbase + (size_t)gh * Wz + gw;
                            fv = F[gi];
                            mv = M[gi];
                        }
                        raw[r][c] = make_float2(fv, mv);
                    }
                    __syncthreads();
                    // ---- W-box: 9-tap sums of the 5 products ----
                    for (int k = tid; k < RAWH * TW; k += NTHREADS) {
                        const int r = k >> 4;
                        const int j = k & 15;
                        float sf = 0.f, sm = 0.f, sff = 0.f, smm = 0.f, sfm = 0.f;
#pragma unroll
                        for (int t = 0; t < 9; ++t) {
                            const float2 fm = raw[r][j + t];
                            sf  += fm.x;
                            sm  += fm.y;
                            sff += fm.x * fm.x;
                            smm += fm.y * fm.y;
                            sfm += fm.x * fm.y;
                        }
                        wbv[r][j] = make_float4(sf, sm, sff, smm);
                        wbs[r][j] = sfm;
                    }
                    __syncthreads();
                    // ---- H-box: 9 taps over W-boxed rows ----
#pragma unroll
                    for (int t = 0; t < 9; ++t) {
                        const float4 v = wbv[th + t][tw];
                        nv0 += v.x; nv1 += v.y; nv2 += v.z; nv3 += v.w;
                        nv4 += wbs[th + t][tw];
                    }
                }
                // ---- rolling D update: compile-time slot q ----
                rs0 += nv0 - circ[q][0]; circ[q][0] = nv0;
                rs1 += nv1 - circ[q][1]; circ[q][1] = nv1;
                rs2 += nv2 - circ[q][2]; circ[q][2] = nv2;
                rs3 += nv3 - circ[q][3]; circ[q][3] = nv3;
                rs4 += nv4 - circ[q][4]; circ[q][4] = nv4;
                if (i >= 8) {                  // out_d = d0 + (i-8)
                    const float inv_n = 1.0f / 729.0f;
                    const float mf   = rs0 * inv_n;
                    const float mm   = rs1 * inv_n;
                    const float varf = rs2 - mf * mf;
                    const float varm = rs3 - mm * mm;
                    const float cov  = rs4 - mf * mm;
                    const float cc = cov * cov / (varf * varm + 1e-8f);
                    cc_acc += cc;
                }
            }
        }
    }

    // ---- fused flow-gradient tail: grid-stride, 15 iters/thread ----
    float sd = 0.f, sh = 0.f, sw = 0.f;
    for (int i4 = bid * NTHREADS + tid; i4 < FLOW_N4; i4 += FSTRIDE) {
        const int base = i4 * 4;                     // < 2^31, safe
        const float4 v = *(const float4*)(X + base);
        const int pos  = base % DHWl;                // const-divisor magic mul
        const int w    = pos % Wz;
        const int rest = pos / Wz;
        const int h    = rest % Hz;
        const int d    = rest / Hz;
        // W diffs (within-row; W divisible by 4 so float4 never crosses a row)
        float s = fabsf(v.y - v.x) + fabsf(v.z - v.y) + fabsf(v.w - v.z);
        if (w > 0) s += fabsf(v.x - X[base - 1]);
        sw += s;
        if (h > 0) {
            const float4 u = *(const float4*)(X + base - Wz);
            sh += fabsf(v.x - u.x) + fabsf(v.y - u.y) + fabsf(v.z - u.z) + fabsf(v.w - u.w);
        }
        if (d > 0) {
            const float4 u = *(const float4*)(X + base - HWl);
            sd += fabsf(v.x - u.x) + fabsf(v.y - u.y) + fabsf(v.z - u.z) + fabsf(v.w - u.w);
        }
    }

    // ---- combined block reduction: {cc, d, h, w} ----
    double v0 = (double)cc_acc, v1 = (double)sd, v2 = (double)sh, v3 = (double)sw;
#pragma unroll
    for (int off = 32; off > 0; off >>= 1) {
        v0 += __shfl_down(v0, off);
        v1 += __shfl_down(v1, off);
        v2 += __shfl_down(v2, off);
        v3 += __shfl_down(v3, off);
    }
    const int wave = tid >> 6, lane = tid & 63;
    if (lane == 0) { wred[0][wave] = v0; wred[1][wave] = v1; wred[2][wave] = v2; wred[3][wave] = v3; }
    __syncthreads();
    if (tid == 0) {
        double t0 = 0.0, t1 = 0.0, t2 = 0.0, t3 = 0.0;
        for (int k = 0; k < NTHREADS / 64; ++k) {
            t0 += wred[0][k]; t1 += wred[1][k]; t2 += wred[2][k]; t3 += wred[3][k];
        }
        double* p = ws + (size_t)(bid % nbuck) * 4;
        atomicAdd(&p[0], t0);
        atomicAdd(&p[1], t1);
        atomicAdd(&p[2], t2);
        atomicAdd(&p[3], t3);
    }
}

__global__ __launch_bounds__(64)
void finalize_kernel(const double* __restrict__ ws, float* __restrict__ out, int nbuck) {
    const int tid = threadIdx.x;
    double cc = 0.0, sd = 0.0, sh = 0.0, sw = 0.0;
    if (tid < nbuck) {
        const double* p = ws + (size_t)tid * 4;
        cc = p[0]; sd = p[1]; sh = p[2]; sw = p[3];
    }
#pragma unroll
    for (int off = 32; off > 0; off >>= 1) {
        cc += __shfl_down(cc, off);
        sd += __shfl_down(sd, off);
        sh += __shfl_down(sh, off);
        sw += __shfl_down(sw, off);
    }
    if (tid == 0) {
        const double n_cc = 9830400.0;           // 2*1*160*192*160
        const double n_dx = 29337600.0;          // H diffs: 2*3*160*191*160
        const double n_dy = 29306880.0;          // D diffs: 2*3*159*192*160
        const double n_dz = 29306880.0;          // W diffs: 2*3*160*192*159
        const double L_sim = -cc / n_cc;
        const double L_reg = sh / n_dx + sd / n_dy + sw / n_dz;
        out[0] = (float)(L_sim + L_reg);
        out[1] = (float)L_sim;
        out[2] = (float)L_reg;
    }
}

extern "C" void kernel_launch(void* const* d_in, const int* in_sizes, int n_in,
                              void* d_out, int out_size, void* d_ws, size_t ws_size,
                              hipStream_t stream) {
    (void)in_sizes; (void)n_in; (void)out_size;
    const float* F = (const float*)d_in[0];   // I_fixed
    const float* M = (const float*)d_in[1];   // I_moved
    const float* X = (const float*)d_in[2];   // flow
    double* ws = (double*)d_ws;
    float* out = (float*)d_out;

    int nbuck = (int)(ws_size / (4 * sizeof(double)));
    if (nbuck > MAXBUCK) nbuck = MAXBUCK;
    if (nbuck < 1) nbuck = 1;

    hipMemsetAsync(d_ws, 0, (size_t)nbuck * 4 * sizeof(double), stream);
    fused_kernel<<<NBLOCKS, NTHREADS, 0, stream>>>(F, M, X, ws, nbuck);
    finalize_kernel<<<1, 64, 0, stream>>>(ws, out, nbuck);
}

// Round 10
// 365.138 us; speedup vs baseline: 1.2195x; 1.0091x over previous
//
#include <hip/hip_runtime.h>

// Problem constants (match reference setup_inputs)
#define Bz 2
#define Dz 160
#define Hz 192
#define Wz 160
#define HWl (Hz*Wz)           // 30720
#define DHWl (Dz*Hz*Wz)       // 4915200

// LNCC tiling: 256-thread blocks, 8x32 in-plane tile, 20-slice D walk.
// R9 post-mortem: conflicts (12.44M) were identical across H-box mapping
// swaps; the zero-conflict reference is R3's geometry where EVERY LDS access
// is a contiguous 32-lane run. Restore that shape at 256 threads:
// unpadded arrays, 32-wide rows, th=tid>>5 / tw=tid&31.
#define TH 8
#define TW 32
#define DT 20
#define RAWH (TH+8)           // 16
#define RAWW (TW+8)           // 40
#define NB_H (Hz/TH)          // 24
#define NB_W (Wz/TW)          // 5
#define NB_D (Dz/DT)          // 8
#define NBLOCKS (Bz*NB_H*NB_W*NB_D)  // 1920
#define NTHREADS 256
#define NSLICE (DT+8)         // 28

// Flow fused as a grid-stride tail over float4s of the flow field.
#define FLOW_N4 ((Bz*3*DHWl)/4)      // 7372800
#define FSTRIDE (NBLOCKS*NTHREADS)   // 491520 -> exactly 15 iters/thread

// ws: nbuck buckets x 4 doubles {cc, d, h, w}; bucketed f64 atomics.
#define MAXBUCK 64

__global__ __launch_bounds__(NTHREADS, 2)
void fused_kernel(const float* __restrict__ F, const float* __restrict__ M,
                  const float* __restrict__ X, double* __restrict__ ws, int nbuck) {
    __shared__ float2 raw[RAWH][RAWW];   // raw slice (f,m); row = 80 dw -> staging addr_dw = 2k, contiguous
    __shared__ float4 wbv[RAWH][TW];     // W-boxed (Sf,Sm,Sff,Smm); UNPADDED stride 32 f4 (R3: 0 conflicts)
    __shared__ float  wbs[RAWH][TW];     // W-boxed Sfm
    __shared__ double wred[4][NTHREADS/64];

    const int bid = blockIdx.x;
    const int dc = bid % NB_D;
    const int wc = (bid / NB_D) % NB_W;
    const int hc = (bid / (NB_D * NB_W)) % NB_H;
    const int b  = bid / (NB_D * NB_W * NB_H);

    const int tid = threadIdx.x;
    const int th = tid >> 5;       // 0..7   output row
    const int tw = tid & 31;       // 0..31  output col (contiguous 32-lane runs)

    const int h0 = hc * TH;
    const int w0 = wc * TW;
    const int d0 = dc * DT;
    const size_t bbase = (size_t)b * DHWl;

    // 9-slice rolling window; all indices compile-time (q from unrolled loop)
    // so SROA keeps it in VGPRs (R1 lesson: runtime slot -> 490MB scratch).
    float circ[9][5];
#pragma unroll
    for (int i = 0; i < 9; ++i)
#pragma unroll
        for (int j = 0; j < 5; ++j) circ[i][j] = 0.f;
    float rs0 = 0.f, rs1 = 0.f, rs2 = 0.f, rs3 = 0.f, rs4 = 0.f;
    float cc_acc = 0.f;

    for (int i0 = 0; i0 < NSLICE; i0 += 9) {
#pragma unroll
        for (int q = 0; q < 9; ++q) {
            const int i = i0 + q;              // slice index within walk
            if (i < NSLICE) {                  // uniform guard
                const int s = d0 - 4 + i;      // global D slice
                float nv0 = 0.f, nv1 = 0.f, nv2 = 0.f, nv3 = 0.f, nv4 = 0.f;
                if (s >= 0 && s < Dz) {        // block-uniform branch
                    __syncthreads();           // protect previous slice's LDS reads
                    // ---- stage raw slice (zero outside volume) ----
                    // addr_dw = 80r + 2c = 2k: contiguous b64 writes, conflict-free
                    const size_t sbase = bbase + (size_t)s * HWl;
                    for (int k = tid; k < RAWH * RAWW; k += NTHREADS) {
                        const int r = k / RAWW;
                        const int c = k - r * RAWW;
                        const int gh = h0 - 4 + r;
                        const int gw = w0 - 4 + c;
                        float fv = 0.f, mv = 0.f;
                        if (gh >= 0 && gh < Hz && gw >= 0 && gw < Wz) {
                            const size_t gi = sbase + (size_t)gh * Wz + gw;
                            fv = F[gi];
                            mv = M[gi];
                        }
                        raw[r][c] = make_float2(fv, mv);
                    }
                    __syncthreads();
                    // ---- W-box: 9-tap sums of the 5 products ----
                    // k>>5 / k&31: 32 lanes share a row -> all reads/writes
                    // are contiguous 32-lane runs (R3's measured-0 pattern)
                    for (int k = tid; k < RAWH * TW; k += NTHREADS) {
                        const int r = k >> 5;
                        const int j = k & 31;
                        float sf = 0.f, sm = 0.f, sff = 0.f, smm = 0.f, sfm = 0.f;
#pragma unroll
                        for (int t = 0; t < 9; ++t) {
                            const float2 fm = raw[r][j + t];
                            sf  += fm.x;
                            sm  += fm.y;
                            sff += fm.x * fm.x;
                            smm += fm.y * fm.y;
                            sfm += fm.x * fm.y;
                        }
                        wbv[r][j] = make_float4(sf, sm, sff, smm);
                        wbs[r][j] = sfm;
                    }
                    __syncthreads();
                    // ---- H-box: 9 taps over W-boxed rows ----
                    // lanes 0..31 read wbv[th+t][0..31]: contiguous 512B runs
#pragma unroll
                    for (int t = 0; t < 9; ++t) {
                        const float4 v = wbv[th + t][tw];
                        nv0 += v.x; nv1 += v.y; nv2 += v.z; nv3 += v.w;
                        nv4 += wbs[th + t][tw];
                    }
                }
                // ---- rolling D update: compile-time slot q ----
                rs0 += nv0 - circ[q][0]; circ[q][0] = nv0;
                rs1 += nv1 - circ[q][1]; circ[q][1] = nv1;
                rs2 += nv2 - circ[q][2]; circ[q][2] = nv2;
                rs3 += nv3 - circ[q][3]; circ[q][3] = nv3;
                rs4 += nv4 - circ[q][4]; circ[q][4] = nv4;
                if (i >= 8) {                  // out_d = d0 + (i-8)
                    const float inv_n = 1.0f / 729.0f;
                    const float mf   = rs0 * inv_n;
                    const float mm   = rs1 * inv_n;
                    const float varf = rs2 - mf * mf;
                    const float varm = rs3 - mm * mm;
                    const float cov  = rs4 - mf * mm;
                    const float cc = cov * cov / (varf * varm + 1e-8f);
                    cc_acc += cc;
                }
            }
        }
    }

    // ---- fused flow-gradient tail: grid-stride, 15 iters/thread ----
    float sd = 0.f, sh = 0.f, sw = 0.f;
    for (int i4 = bid * NTHREADS + tid; i4 < FLOW_N4; i4 += FSTRIDE) {
        const int base = i4 * 4;                     // < 2^31, safe
        const float4 v = *(const float4*)(X + base);
        const int pos  = base % DHWl;                // const-divisor magic mul
        const int w    = pos % Wz;
        const int rest = pos / Wz;
        const int h    = rest % Hz;
        const int d    = rest / Hz;
        // W diffs (within-row; W divisible by 4 so float4 never crosses a row)
        float s = fabsf(v.y - v.x) + fabsf(v.z - v.y) + fabsf(v.w - v.z);
        if (w > 0) s += fabsf(v.x - X[base - 1]);
        sw += s;
        if (h > 0) {
            const float4 u = *(const float4*)(X + base - Wz);
            sh += fabsf(v.x - u.x) + fabsf(v.y - u.y) + fabsf(v.z - u.z) + fabsf(v.w - u.w);
        }
        if (d > 0) {
            const float4 u = *(const float4*)(X + base - HWl);
            sd += fabsf(v.x - u.x) + fabsf(v.y - u.y) + fabsf(v.z - u.z) + fabsf(v.w - u.w);
        }
    }

    // ---- combined block reduction: {cc, d, h, w} ----
    double v0 = (double)cc_acc, v1 = (double)sd, v2 = (double)sh, v3 = (double)sw;
#pragma unroll
    for (int off = 32; off > 0; off >>= 1) {
        v0 += __shfl_down(v0, off);
        v1 += __shfl_down(v1, off);
        v2 += __shfl_down(v2, off);
        v3 += __shfl_down(v3, off);
    }
    const int wave = tid >> 6, lane = tid & 63;
    if (lane == 0) { wred[0][wave] = v0; wred[1][wave] = v1; wred[2][wave] = v2; wred[3][wave] = v3; }
    __syncthreads();
    if (tid == 0) {
        double t0 = 0.0, t1 = 0.0, t2 = 0.0, t3 = 0.0;
        for (int k = 0; k < NTHREADS / 64; ++k) {
            t0 += wred[0][k]; t1 += wred[1][k]; t2 += wred[2][k]; t3 += wred[3][k];
        }
        double* p = ws + (size_t)(bid % nbuck) * 4;
        atomicAdd(&p[0], t0);
        atomicAdd(&p[1], t1);
        atomicAdd(&p[2], t2);
        atomicAdd(&p[3], t3);
    }
}

__global__ __launch_bounds__(64)
void finalize_kernel(const double* __restrict__ ws, float* __restrict__ out, int nbuck) {
    const int tid = threadIdx.x;
    double cc = 0.0, sd = 0.0, sh = 0.0, sw = 0.0;
    if (tid < nbuck) {
        const double* p = ws + (size_t)tid * 4;
        cc = p[0]; sd = p[1]; sh = p[2]; sw = p[3];
    }
#pragma unroll
    for (int off = 32; off > 0; off >>= 1) {
        cc += __shfl_down(cc, off);
        sd += __shfl_down(sd, off);
        sh += __shfl_down(sh, off);
        sw += __shfl_down(sw, off);
    }
    if (tid == 0) {
        const double n_cc = 9830400.0;           // 2*1*160*192*160
        const double n_dx = 29337600.0;          // H diffs: 2*3*160*191*160
        const double n_dy = 29306880.0;          // D diffs: 2*3*159*192*160
        const double n_dz = 29306880.0;          // W diffs: 2*3*160*192*159
        const double L_sim = -cc / n_cc;
        const double L_reg = sh / n_dx + sd / n_dy + sw / n_dz;
        out[0] = (float)(L_sim + L_reg);
        out[1] = (float)L_sim;
        out[2] = (float)L_reg;
    }
}

extern "C" void kernel_launch(void* const* d_in, const int* in_sizes, int n_in,
                              void* d_out, int out_size, void* d_ws, size_t ws_size,
                              hipStream_t stream) {
    (void)in_sizes; (void)n_in; (void)out_size;
    const float* F = (const float*)d_in[0];   // I_fixed
    const float* M = (const float*)d_in[1];   // I_moved
    const float* X = (const float*)d_in[2];   // flow
    double* ws = (double*)d_ws;
    float* out = (float*)d_out;

    int nbuck = (int)(ws_size / (4 * sizeof(double)));
    if (nbuck > MAXBUCK) nbuck = MAXBUCK;
    if (nbuck < 1) nbuck = 1;

    hipMemsetAsync(d_ws, 0, (size_t)nbuck * 4 * sizeof(double), stream);
    fused_kernel<<<NBLOCKS, NTHREADS, 0, stream>>>(F, M, X, ws, nbuck);
    finalize_kernel<<<1, 64, 0, stream>>>(ws, out, nbuck);
}

// Round 11
// 311.776 us; speedup vs baseline: 1.4282x; 1.1712x over previous
//
#include <hip/hip_runtime.h>

// Problem constants (match reference setup_inputs)
#define Bz 2
#define Dz 160
#define Hz 192
#define Wz 160
#define HWl (Hz*Wz)           // 30720
#define DHWl (Dz*Hz*Wz)       // 4915200

// LNCC tiling: 256-thread blocks, 8x32 in-plane tile (R10: zero-conflict
// geometry, every LDS access a contiguous 32-lane run), 20-slice D walk.
// R10 post-mortem: conflicts 12.4M->0 but dur unchanged -> critical path is
// the exposed global-load latency before the stage barrier. This round:
// prefetch slice i+1 into registers while slice i computes (T14 split).
#define TH 8
#define TW 32
#define DT 20
#define RAWH (TH+8)           // 16
#define RAWW (TW+8)           // 40
#define NB_H (Hz/TH)          // 24
#define NB_W (Wz/TW)          // 5
#define NB_D (Dz/DT)          // 8
#define NBLOCKS (Bz*NB_H*NB_W*NB_D)  // 1920
#define NTHREADS 256
#define NSLICE (DT+8)         // 28
#define RAWN (RAWH*RAWW)      // 640 -> 2.5 elems/thread, 3 static slots

// Flow fused as a grid-stride tail over float4s of the flow field.
#define FLOW_N4 ((Bz*3*DHWl)/4)      // 7372800
#define FSTRIDE (NBLOCKS*NTHREADS)   // 491520 -> exactly 15 iters/thread

// ws: nbuck buckets x 4 doubles {cc, d, h, w}; bucketed f64 atomics.
#define MAXBUCK 64

__global__ __launch_bounds__(NTHREADS, 2)
void fused_kernel(const float* __restrict__ F, const float* __restrict__ M,
                  const float* __restrict__ X, double* __restrict__ ws, int nbuck) {
    __shared__ float2 raw[RAWH][RAWW];   // raw slice (f,m)
    __shared__ float4 wbv[RAWH][TW];     // W-boxed (Sf,Sm,Sff,Smm); unpadded (R10: 0 conflicts)
    __shared__ float  wbs[RAWH][TW];     // W-boxed Sfm
    __shared__ double wred[4][NTHREADS/64];

    const int bid = blockIdx.x;
    const int dc = bid % NB_D;
    const int wc = (bid / NB_D) % NB_W;
    const int hc = (bid / (NB_D * NB_W)) % NB_H;
    const int b  = bid / (NB_D * NB_W * NB_H);

    const int tid = threadIdx.x;
    const int th = tid >> 5;       // 0..7   output row
    const int tw = tid & 31;       // 0..31  output col

    const int h0 = hc * TH;
    const int w0 = wc * TW;
    const int d0 = dc * DT;
    const size_t bbase = (size_t)b * DHWl;

    // Per-thread staging slots (static indices only -> registers).
    float pf_f[3], pf_m[3];

    // Prefetch slice i_ (global s = d0-4+i_) into pf regs; zero outside.
#define PREFETCH(i_) do {                                                   \
        const int s_ = d0 - 4 + (i_);                                       \
        const bool sv_ = ((i_) < NSLICE) && (s_ >= 0) && (s_ < Dz);         \
        _Pragma("unroll")                                                   \
        for (int e = 0; e < 3; ++e) {                                       \
            const int k_ = tid + e * NTHREADS;                              \
            float fv_ = 0.f, mv_ = 0.f;                                     \
            if (sv_ && k_ < RAWN) {                                         \
                const int r_ = k_ / RAWW;                                   \
                const int c_ = k_ - r_ * RAWW;                              \
                const int gh_ = h0 - 4 + r_;                                \
                const int gw_ = w0 - 4 + c_;                                \
                if (gh_ >= 0 && gh_ < Hz && gw_ >= 0 && gw_ < Wz) {         \
                    const size_t gi_ = bbase + (size_t)s_ * HWl             \
                                     + (size_t)gh_ * Wz + gw_;              \
                    fv_ = F[gi_];                                           \
                    mv_ = M[gi_];                                           \
                }                                                           \
            }                                                               \
            pf_f[e] = fv_; pf_m[e] = mv_;                                   \
        }                                                                   \
    } while (0)

    // 9-slice rolling window; compile-time slot q (R1 lesson: runtime slot
    // -> scratch spill, 490MB of traffic).
    float circ[9][5];
#pragma unroll
    for (int i = 0; i < 9; ++i)
#pragma unroll
        for (int j = 0; j < 5; ++j) circ[i][j] = 0.f;
    float rs0 = 0.f, rs1 = 0.f, rs2 = 0.f, rs3 = 0.f, rs4 = 0.f;
    float cc_acc = 0.f;

    PREFETCH(0);

    for (int i0 = 0; i0 < NSLICE; i0 += 9) {
#pragma unroll
        for (int q = 0; q < 9; ++q) {
            const int i = i0 + q;              // slice index within walk
            if (i < NSLICE) {                  // uniform guard
                const int s = d0 - 4 + i;      // global D slice
                const bool sv = (s >= 0 && s < Dz);   // block-uniform
                float nv0 = 0.f, nv1 = 0.f, nv2 = 0.f, nv3 = 0.f, nv4 = 0.f;
                if (sv) {
                    __syncthreads();           // protect prev slice's LDS reads
                    // ---- drain prefetched regs into raw ----
#pragma unroll
                    for (int e = 0; e < 3; ++e) {
                        const int k = tid + e * NTHREADS;
                        if (k < RAWN) {
                            const int r = k / RAWW;
                            const int c = k - r * RAWW;
                            raw[r][c] = make_float2(pf_f[e], pf_m[e]);
                        }
                    }
                }
                // ---- issue next slice's loads; latency hides under W/H-box ----
                PREFETCH(i + 1);
                if (sv) {
                    __syncthreads();
                    // ---- W-box: 9-tap sums of the 5 products ----
                    for (int k = tid; k < RAWH * TW; k += NTHREADS) {
                        const int r = k >> 5;
                        const int j = k & 31;
                        float sf = 0.f, sm = 0.f, sff = 0.f, smm = 0.f, sfm = 0.f;
#pragma unroll
                        for (int t = 0; t < 9; ++t) {
                            const float2 fm = raw[r][j + t];
                            sf  += fm.x;
                            sm  += fm.y;
                            sff += fm.x * fm.x;
                            smm += fm.y * fm.y;
                            sfm += fm.x * fm.y;
                        }
                        wbv[r][j] = make_float4(sf, sm, sff, smm);
                        wbs[r][j] = sfm;
                    }
                    __syncthreads();
                    // ---- H-box: 9 taps over W-boxed rows (contiguous runs) ----
#pragma unroll
                    for (int t = 0; t < 9; ++t) {
                        const float4 v = wbv[th + t][tw];
                        nv0 += v.x; nv1 += v.y; nv2 += v.z; nv3 += v.w;
                        nv4 += wbs[th + t][tw];
                    }
                }
                // ---- rolling D update: compile-time slot q ----
                rs0 += nv0 - circ[q][0]; circ[q][0] = nv0;
                rs1 += nv1 - circ[q][1]; circ[q][1] = nv1;
                rs2 += nv2 - circ[q][2]; circ[q][2] = nv2;
                rs3 += nv3 - circ[q][3]; circ[q][3] = nv3;
                rs4 += nv4 - circ[q][4]; circ[q][4] = nv4;
                if (i >= 8) {                  // out_d = d0 + (i-8)
                    const float inv_n = 1.0f / 729.0f;
                    const float mf   = rs0 * inv_n;
                    const float mm   = rs1 * inv_n;
                    const float varf = rs2 - mf * mf;
                    const float varm = rs3 - mm * mm;
                    const float cov  = rs4 - mf * mm;
                    const float cc = cov * cov / (varf * varm + 1e-8f);
                    cc_acc += cc;
                }
            }
        }
    }

    // ---- fused flow-gradient tail: grid-stride, 15 iters/thread ----
    float sd = 0.f, sh = 0.f, sw = 0.f;
    for (int i4 = bid * NTHREADS + tid; i4 < FLOW_N4; i4 += FSTRIDE) {
        const int base = i4 * 4;                     // < 2^31, safe
        const float4 v = *(const float4*)(X + base);
        const int pos  = base % DHWl;                // const-divisor magic mul
        const int w    = pos % Wz;
        const int rest = pos / Wz;
        const int h    = rest % Hz;
        const int d    = rest / Hz;
        // W diffs (within-row; W divisible by 4 so float4 never crosses a row)
        float s = fabsf(v.y - v.x) + fabsf(v.z - v.y) + fabsf(v.w - v.z);
        if (w > 0) s += fabsf(v.x - X[base - 1]);
        sw += s;
        if (h > 0) {
            const float4 u = *(const float4*)(X + base - Wz);
            sh += fabsf(v.x - u.x) + fabsf(v.y - u.y) + fabsf(v.z - u.z) + fabsf(v.w - u.w);
        }
        if (d > 0) {
            const float4 u = *(const float4*)(X + base - HWl);
            sd += fabsf(v.x - u.x) + fabsf(v.y - u.y) + fabsf(v.z - u.z) + fabsf(v.w - u.w);
        }
    }

    // ---- combined block reduction: {cc, d, h, w} ----
    double v0 = (double)cc_acc, v1 = (double)sd, v2 = (double)sh, v3 = (double)sw;
#pragma unroll
    for (int off = 32; off > 0; off >>= 1) {
        v0 += __shfl_down(v0, off);
        v1 += __shfl_down(v1, off);
        v2 += __shfl_down(v2, off);
        v3 += __shfl_down(v3, off);
    }
    const int wave = tid >> 6, lane = tid & 63;
    if (lane == 0) { wred[0][wave] = v0; wred[1][wave] = v1; wred[2][wave] = v2; wred[3][wave] = v3; }
    __syncthreads();
    if (tid == 0) {
        double t0 = 0.0, t1 = 0.0, t2 = 0.0, t3 = 0.0;
        for (int k = 0; k < NTHREADS / 64; ++k) {
            t0 += wred[0][k]; t1 += wred[1][k]; t2 += wred[2][k]; t3 += wred[3][k];
        }
        double* p = ws + (size_t)(bid % nbuck) * 4;
        atomicAdd(&p[0], t0);
        atomicAdd(&p[1], t1);
        atomicAdd(&p[2], t2);
        atomicAdd(&p[3], t3);
    }
}

__global__ __launch_bounds__(64)
void finalize_kernel(const double* __restrict__ ws, float* __restrict__ out, int nbuck) {
    const int tid = threadIdx.x;
    double cc = 0.0, sd = 0.0, sh = 0.0, sw = 0.0;
    if (tid < nbuck) {
        const double* p = ws + (size_t)tid * 4;
        cc = p[0]; sd = p[1]; sh = p[2]; sw = p[3];
    }
#pragma unroll
    for (int off = 32; off > 0; off >>= 1) {
        cc += __shfl_down(cc, off);
        sd += __shfl_down(sd, off);
        sh += __shfl_down(sh, off);
        sw += __shfl_down(sw, off);
    }
    if (tid == 0) {
        const double n_cc = 9830400.0;           // 2*1*160*192*160
        const double n_dx = 29337600.0;          // H diffs: 2*3*160*191*160
        const double n_dy = 29306880.0;          // D diffs: 2*3*159*192*160
        const double n_dz = 29306880.0;          // W diffs: 2*3*160*192*159
        const double L_sim = -cc / n_cc;
        const double L_reg = sh / n_dx + sd / n_dy + sw / n_dz;
        out[0] = (float)(L_sim + L_reg);
        out[1] = (float)L_sim;
        out[2] = (float)L_reg;
    }
}

extern "C" void kernel_launch(void* const* d_in, const int* in_sizes, int n_in,
                              void* d_out, int out_size, void* d_ws, size_t ws_size,
                              hipStream_t stream) {
    (void)in_sizes; (void)n_in; (void)out_size;
    const float* F = (const float*)d_in[0];   // I_fixed
    const float* M = (const float*)d_in[1];   // I_moved
    const float* X = (const float*)d_in[2];   // flow
    double* ws = (double*)d_ws;
    float* out = (float*)d_out;

    int nbuck = (int)(ws_size / (4 * sizeof(double)));
    if (nbuck > MAXBUCK) nbuck = MAXBUCK;
    if (nbuck < 1) nbuck = 1;

    hipMemsetAsync(d_ws, 0, (size_t)nbuck * 4 * sizeof(double), stream);
    fused_kernel<<<NBLOCKS, NTHREADS, 0, stream>>>(F, M, X, ws, nbuck);
    finalize_kernel<<<1, 64, 0, stream>>>(ws, out, nbuck);
}